// Round 12
// baseline (55.045 us; speedup 1.0000x reference)
//
#include <hip/hip_runtime.h>
#include <hip/hip_bf16.h>

// B=32, N=64, D=128, H=256
typedef __attribute__((ext_vector_type(8))) _Float16 half8;
typedef __attribute__((ext_vector_type(4))) float f32x4;

// ---------------------------------------------------------------------------
// Prep (R4): blocks 0..255  : L/R = objects @ gW1(top/bottom), 8 rows each.
//              Lh = fp16(L + gb1)  [row][k] linear (512B rows)
//              Rh = fp16(R)        rows of 512B, 16B-units XOR-swizzled:
//                                  byte = row*512 + (2k ^ ((row&15)<<4))
//            blocks 256..271: transpose gW2 -> W2h[col][k] fp16
//            block  272     : zero S
// ---------------------------------------------------------------------------
__global__ __launch_bounds__(256) void rn_prep(
    const float* __restrict__ obj, const float* __restrict__ gW1,
    const float* __restrict__ gb1, const float* __restrict__ gW2,
    _Float16* __restrict__ Lh, char* __restrict__ RhB,
    _Float16* __restrict__ W2h, float* __restrict__ S)
{
    __shared__ float so[8 * 128];
    __shared__ float tt[64 * 65];
    const int blk = blockIdx.x, t = threadIdx.x;

    if (blk < 256) {
        const int r0 = blk * 8;
        #pragma unroll
        for (int it = 0; it < 4; ++it) so[it * 256 + t] = obj[r0 * 128 + it * 256 + t];
        __syncthreads();
        float accL[8], accR[8];
        #pragma unroll
        for (int r = 0; r < 8; ++r) { accL[r] = 0.f; accR[r] = 0.f; }
        for (int k = 0; k < 128; ++k) {
            float wL = gW1[k * 256 + t];
            float wR = gW1[(128 + k) * 256 + t];
            #pragma unroll
            for (int r = 0; r < 8; ++r) {
                float o = so[r * 128 + k];
                accL[r] += o * wL;
                accR[r] += o * wR;
            }
        }
        float bb = gb1[t];
        #pragma unroll
        for (int r = 0; r < 8; ++r) {
            int row = r0 + r;
            Lh[row * 256 + t] = (_Float16)(accL[r] + bb);
            *(_Float16*)(RhB + row * 512 + ((2 * t) ^ ((row & 15) << 4))) = (_Float16)accR[r];
        }
    } else if (blk < 272) {
        const int tb = blk - 256;
        const int k0 = (tb >> 2) * 64, c0 = (tb & 3) * 64;
        for (int it = 0; it < 16; ++it) {
            int idx = it * 256 + t, rr = idx >> 6, cc = idx & 63;
            tt[rr * 65 + cc] = gW2[(k0 + rr) * 256 + c0 + cc];
        }
        __syncthreads();
        for (int it = 0; it < 16; ++it) {
            int idx = it * 256 + t, cr = idx >> 6, kk = idx & 63;
            W2h[(c0 + cr) * 256 + (k0 + kk)] = (_Float16)tt[kk * 65 + cr];
        }
    } else {
        for (int it = 0; it < 32; ++it) S[it * 256 + t] = 0.f;
    }
}

// ---------------------------------------------------------------------------
// Main (OCCUPANCY redesign): grid 512 = (b 32) x (ig 8) x (half 2);
// block 1024 thr = 16 waves = (mr 4) x (nc 4). Wave tile: rows [mr*16,+16),
// cols [half*128 + nc*32, +32); 8 i's per block. Per-wave state: bfr[2][8]
// (64 VGPR) + rh[8] (32) + acc[2] (8) ~= 104 core, ~125 total -> fits the
// hard 128-VGPR cap of a 1024-thr block => 8 waves/SIMD, 2 blocks/CU (LDS
// 36KB, 2048 thr/CU). Same arithmetic as R4, 4x the latency hiding.
// A-frag in regs: pk_max(pk_add(lh,rh),0); mfma_f32_16x16x32_f16.
// ---------------------------------------------------------------------------
__global__ __launch_bounds__(1024) void rn_main(
    const char* __restrict__ LhB, const char* __restrict__ RhB,
    const _Float16* __restrict__ W2h, const float* __restrict__ gb2,
    float* __restrict__ S)
{
    __shared__ __attribute__((aligned(16))) char smem[36864];  // Rh 32KB + Lh 4KB
    const int blk = blockIdx.x;               // 512 = 32 b x 8 ig x 2 half
    const int b = blk >> 4, ig = (blk >> 1) & 7, half = blk & 1;
    const int t = threadIdx.x, lane = t & 63, w = t >> 6;
    const int mr = w & 3, nc = w >> 2;        // mr: row-tile, nc: col-tile
    const int lc = lane & 15, lg = lane >> 4;

    // issue register-resident B loads first (L2 latency hides under staging)
    half8 bfr[2][8];
    #pragma unroll
    for (int n = 0; n < 2; ++n)
        #pragma unroll
        for (int ks = 0; ks < 8; ++ks)
            bfr[n][ks] = *(const half8*)(W2h +
                (half * 128 + nc * 32 + n * 16 + lc) * 256 + ks * 32 + lg * 8);

    float bias[2];
    #pragma unroll
    for (int n = 0; n < 2; ++n) bias[n] = gb2[half * 128 + nc * 32 + n * 16 + lc];

    {   // stage Rh[b] (pre-swizzled, linear copy) + Lh rows ig*8..+8
        const char* gR = RhB + b * 32768;
        #pragma unroll
        for (int it = 0; it < 2; ++it) {
            int u = it * 1024 + t;
            *(f32x4*)(smem + u * 16) = *(const f32x4*)(gR + u * 16);
        }
        if (t < 256) {
            const char* gL = LhB + (b * 64 + ig * 8) * 512;
            *(f32x4*)(smem + 32768 + t * 16) = *(const f32x4*)(gL + t * 16);
        }
    }
    __syncthreads();

    // hoist this wave's 16 Rh rows into regs (ii-invariant): 8 ks
    half8 rh[8];
    {
        int row = mr * 16 + lc;
        #pragma unroll
        for (int ks = 0; ks < 8; ++ks) {
            int kb = ks * 64 + lg * 16;
            rh[ks] = *(const half8*)(smem + row * 512 + (kb ^ (lc << 4)));
        }
    }

    const half8 zero8 = {(_Float16)0.f, (_Float16)0.f, (_Float16)0.f, (_Float16)0.f,
                         (_Float16)0.f, (_Float16)0.f, (_Float16)0.f, (_Float16)0.f};
    float csum[2] = {0.f, 0.f};

    #pragma unroll 1
    for (int ii = 0; ii < 8; ++ii) {
        f32x4 acc0 = (f32x4){0.f, 0.f, 0.f, 0.f};
        f32x4 acc1 = (f32x4){0.f, 0.f, 0.f, 0.f};

        #pragma unroll
        for (int ks = 0; ks < 8; ++ks) {
            half8 lhv = *(const half8*)(smem + 32768 + ii * 512 + ks * 64 + lg * 16);
            half8 av = __builtin_elementwise_max(lhv + rh[ks], zero8);
            acc0 = __builtin_amdgcn_mfma_f32_16x16x32_f16(av, bfr[0][ks], acc0, 0, 0, 0);
            acc1 = __builtin_amdgcn_mfma_f32_16x16x32_f16(av, bfr[1][ks], acc1, 0, 0, 0);
        }

        const int iglob = ig * 8 + ii;
        #pragma unroll
        for (int q = 0; q < 4; ++q) {
            int row = mr * 16 + lg * 4 + q;   // = j
            float v0 = fmaxf(acc0[q] + bias[0], 0.f);
            float v1 = fmaxf(acc1[q] + bias[1], 0.f);
            csum[0] += (row == iglob) ? 0.f : v0;
            csum[1] += (row == iglob) ? 0.f : v1;
        }
    }

    #pragma unroll
    for (int n = 0; n < 2; ++n) {
        float cs = csum[n];
        cs += __shfl_xor(cs, 16);
        cs += __shfl_xor(cs, 32);
        if (lane < 16)
            atomicAdd(&S[b * 256 + half * 128 + nc * 32 + n * 16 + lc], cs);
    }
}

// ---------------------------------------------------------------------------
// Final (R4): block per b, 1024 thr = (64 col-groups of 4) x (16 kq). Three
// chained matvecs; per phase 16 independent float4 loads, padded-LDS reduce.
// ---------------------------------------------------------------------------
__global__ __launch_bounds__(1024) void rn_final(
    const float* __restrict__ S, const float* __restrict__ gW3,
    const float* __restrict__ gb3, const float* __restrict__ fW1,
    const float* __restrict__ fb1, const float* __restrict__ fW2,
    const float* __restrict__ fb2, float* __restrict__ out)
{
    __shared__ float vec[256];
    __shared__ float ps[16][260];
    const int b = blockIdx.x, t = threadIdx.x;
    const int cg = t & 63, kq = t >> 6;
    const int c0 = cg * 4;

    if (t < 256) vec[t] = S[b * 256 + t];
    __syncthreads();

    {
        f32x4 s = (f32x4){0.f, 0.f, 0.f, 0.f};
        #pragma unroll
        for (int kk = 0; kk < 16; ++kk) {
            int k = kq * 16 + kk;
            s += (*(const f32x4*)&gW3[k * 256 + c0]) * vec[k];
        }
        *(f32x4*)&ps[kq][c0] = s;
    }
    __syncthreads();
    if (t < 256) {
        float a = 0.f;
        #pragma unroll
        for (int q = 0; q < 16; ++q) a += ps[q][t];
        vec[t] = a + 4032.0f * gb3[t];
    }
    __syncthreads();

    {
        f32x4 s = (f32x4){0.f, 0.f, 0.f, 0.f};
        #pragma unroll
        for (int kk = 0; kk < 16; ++kk) {
            int k = kq * 16 + kk;
            s += (*(const f32x4*)&fW1[k * 256 + c0]) * vec[k];
        }
        *(f32x4*)&ps[kq][c0] = s;
    }
    __syncthreads();
    if (t < 256) {
        float a = 0.f;
        #pragma unroll
        for (int q = 0; q < 16; ++q) a += ps[q][t];
        vec[t] = fmaxf(a + fb1[t], 0.f);
    }
    __syncthreads();

    {
        f32x4 s = (f32x4){0.f, 0.f, 0.f, 0.f};
        #pragma unroll
        for (int kk = 0; kk < 16; ++kk) {
            int k = kq * 16 + kk;
            s += (*(const f32x4*)&fW2[k * 256 + c0]) * vec[k];
        }
        *(f32x4*)&ps[kq][c0] = s;
    }
    __syncthreads();
    if (t < 256) {
        float a = 0.f;
        #pragma unroll
        for (int q = 0; q < 16; ++q) a += ps[q][t];
        out[b * 256 + t] = a + fb2[t];
    }
}

extern "C" void kernel_launch(void* const* d_in, const int* in_sizes, int n_in,
                              void* d_out, int out_size, void* d_ws, size_t ws_size,
                              hipStream_t stream)
{
    const float* obj = (const float*)d_in[0];
    const float* gW1 = (const float*)d_in[1];
    const float* gb1 = (const float*)d_in[2];
    const float* gW2 = (const float*)d_in[3];
    const float* gb2 = (const float*)d_in[4];
    const float* gW3 = (const float*)d_in[5];
    const float* gb3 = (const float*)d_in[6];
    const float* fW1 = (const float*)d_in[7];
    const float* fb1 = (const float*)d_in[8];
    const float* fW2 = (const float*)d_in[9];
    const float* fb2 = (const float*)d_in[10];
    float* out = (float*)d_out;

    char* ws = (char*)d_ws;
    _Float16* Lh  = (_Float16*)(ws);                           // 1 MB
    char*     RhB = ws + (1u << 20);                           // 1 MB (swizzled fp16)
    _Float16* W2h = (_Float16*)(ws + (2u << 20));              // 128 KB
    float*    S   = (float*)(ws + (2u << 20) + (128u << 10));  // 32 KB

    rn_prep <<<273, 256, 0, stream>>>(obj, gW1, gb1, gW2, Lh, RhB, W2h, S);
    rn_main <<<512, 1024, 0, stream>>>((const char*)Lh, RhB, W2h, gb2, S);
    rn_final<<<32, 1024, 0, stream>>>(S, gW3, gb3, fW1, fb1, fW2, fb2, out);
}